// Round 1
// baseline (222.045 us; speedup 1.0000x reference)
//
#include <hip/hip_runtime.h>

#define Bn 4
#define Cn 256
#define Dn 32
#define Nn 4096

typedef __attribute__((ext_vector_type(8))) short short8;
typedef __attribute__((ext_vector_type(4))) float f32x4;

__device__ __forceinline__ unsigned short f2bf(float f) {
  union { float f; unsigned u; } v; v.f = f;
  unsigned r = v.u + 0x7fffu + ((v.u >> 16) & 1u);   // RNE
  return (unsigned short)(r >> 16);
}

// ---------------------------------------------------------------------------
// Projection kernel: out[b][e][n] = sum_c W[e][c]*in[b][c][n] + bias[e]
// Sections: bid<64 -> q (W=Wq,in=x), bid<128 -> k (Wk,y), else v (Wv,z).
// q/k written as [B][N][32] bf16 (row-per-position), v as [B][C][N] bf16.
// Block = [32 e x 256 n], 4 waves (64 n each). MFMA 16x16x32 bf16.
// k-map convention (both operands, everywhere in this file):
//   frag slot j (lane group g=lane>>4): k = 4g+j for j<4, k = 16+4g+(j-4) else.
// ---------------------------------------------------------------------------
__global__ __launch_bounds__(256) void SA_proj(
    const float* __restrict__ x, const float* __restrict__ y, const float* __restrict__ z,
    const float* __restrict__ Wq, const float* __restrict__ bq,
    const float* __restrict__ Wk, const float* __restrict__ bk,
    const float* __restrict__ Wv, const float* __restrict__ bv,
    unsigned short* __restrict__ qws, unsigned short* __restrict__ kws,
    unsigned short* __restrict__ vws)
{
  __shared__ char lds[256 * 80];   // 20480 B; reused for both repack layouts
  const int bid = blockIdx.x, tid = threadIdx.x;
  const int lane = tid & 63, w = tid >> 6;
  const int g = lane >> 4, l15 = lane & 15;

  const float *W, *in, *bias; unsigned short* outp;
  int b, e0, n0, isv;
  if (bid < 64)       { b = bid >> 4;              n0 = (bid & 15) << 8; e0 = 0;               W = Wq; in = x; bias = bq; outp = qws; isv = 0; }
  else if (bid < 128) { int t = bid - 64; b = t >> 4; n0 = (t & 15) << 8; e0 = 0;             W = Wk; in = y; bias = bk; outp = kws; isv = 0; }
  else                { int t = bid - 128; b = t >> 7; int r = t & 127; e0 = (r >> 4) << 5; n0 = (r & 15) << 8; W = Wv; in = z; bias = bv; outp = vws; isv = 1; }

  const float* inb = in + (size_t)b * Cn * Nn;
  const int nw = n0 + (w << 6);

  f32x4 acc[2][4];
#pragma unroll
  for (int et = 0; et < 2; ++et)
#pragma unroll
    for (int ns = 0; ns < 4; ++ns) { acc[et][ns][0]=0.f; acc[et][ns][1]=0.f; acc[et][ns][2]=0.f; acc[et][ns][3]=0.f; }

  for (int ch = 0; ch < 8; ++ch) {          // K loop over c in chunks of 32
    short8 af[2];
#pragma unroll
    for (int et = 0; et < 2; ++et) {        // A = W rows e (lane row = l15)
      const float* wp = W + (size_t)(e0 + 16*et + l15) * 256 + ch*32 + 4*g;
      float4 a0 = *(const float4*)wp;        // c = 32ch+4g .. +3
      float4 a1 = *(const float4*)(wp + 16); // c = 32ch+16+4g .. +3
      short8 t8;
      t8[0]=(short)f2bf(a0.x); t8[1]=(short)f2bf(a0.y); t8[2]=(short)f2bf(a0.z); t8[3]=(short)f2bf(a0.w);
      t8[4]=(short)f2bf(a1.x); t8[5]=(short)f2bf(a1.y); t8[6]=(short)f2bf(a1.z); t8[7]=(short)f2bf(a1.w);
      af[et] = t8;
    }
    short8 bfr[4];
#pragma unroll
    for (int ns = 0; ns < 4; ++ns) {        // B = in cols n (lane col = l15)
      int n = nw + 16*ns + l15;
      const float* ip  = inb + (size_t)(ch*32 + 4*g) * Nn + n;
      const float* ip2 = ip + (size_t)16 * Nn;
      short8 t8;
      t8[0]=(short)f2bf(ip[0]);  t8[1]=(short)f2bf(ip[Nn]);  t8[2]=(short)f2bf(ip[2*Nn]);  t8[3]=(short)f2bf(ip[3*Nn]);
      t8[4]=(short)f2bf(ip2[0]); t8[5]=(short)f2bf(ip2[Nn]); t8[6]=(short)f2bf(ip2[2*Nn]); t8[7]=(short)f2bf(ip2[3*Nn]);
      bfr[ns] = t8;
    }
#pragma unroll
    for (int et = 0; et < 2; ++et)
#pragma unroll
      for (int ns = 0; ns < 4; ++ns)
        acc[et][ns] = __builtin_amdgcn_mfma_f32_16x16x32_bf16(af[et], bfr[ns], acc[et][ns], 0, 0, 0);
  }

  float bvv[2][4];
#pragma unroll
  for (int et = 0; et < 2; ++et)
#pragma unroll
    for (int r = 0; r < 4; ++r) bvv[et][r] = bias[e0 + 16*et + 4*g + r];

  // C/D layout (HW-verified): col = l15, row-within-tile = 4g + reg.
  if (!isv) {
    // repack to [n][d] (rows 80 B padded), then coalesced store [B][N][32]
#pragma unroll
    for (int et = 0; et < 2; ++et)
#pragma unroll
      for (int ns = 0; ns < 4; ++ns) {
        int nl = (w << 6) + 16*ns + l15;
#pragma unroll
        for (int r = 0; r < 4; ++r) {
          int d = 16*et + 4*g + r;
          *(unsigned short*)(lds + (size_t)nl*80 + d*2) = f2bf(acc[et][ns][r] + bvv[et][r]);
        }
      }
    __syncthreads();
    unsigned short* ob = outp + (size_t)b * Nn * Dn;
#pragma unroll
    for (int i = 0; i < 4; ++i) {
      int idx = i*256 + tid, nl = idx >> 2, c4 = idx & 3;
      *(uint4*)((char*)ob + (size_t)(n0 + nl)*64 + c4*16) = *(const uint4*)(lds + (size_t)nl*80 + c4*16);
    }
  } else {
    // repack to [e][n] (rows 528 B padded), then coalesced store [B][C][N]
#pragma unroll
    for (int et = 0; et < 2; ++et)
#pragma unroll
      for (int ns = 0; ns < 4; ++ns) {
        int nl = (w << 6) + 16*ns + l15;
#pragma unroll
        for (int r = 0; r < 4; ++r) {
          int el = 16*et + 4*g + r;
          *(unsigned short*)(lds + (size_t)el*528 + nl*2) = f2bf(acc[et][ns][r] + bvv[et][r]);
        }
      }
    __syncthreads();
#pragma unroll
    for (int i = 0; i < 4; ++i) {
      int idx = i*256 + tid, el = idx >> 5, c16 = idx & 31;
      *(uint4*)((char*)vws + (size_t)b * Cn * Nn * 2 + (size_t)(e0 + el) * Nn * 2 + (size_t)n0*2 + c16*16)
          = *(const uint4*)(lds + (size_t)el*528 + c16*16);
    }
  }
}

// ---------------------------------------------------------------------------
// Flash attention + residual. Grid 256 = 4 batches x 64 query-blocks (64 q).
// Swapped QK^T: S^T = mfma(A=K, B=Q) so lane owns query column m = lane&15.
// K tile [64 n][32 d] rows 80 B, V tile [256 e][64 n] rows 144 B, both stored
// permuted to the frag k-map so frag loads are single b128/b-aligned reads.
// Register prefetch of next tile overlaps global latency with compute.
// ---------------------------------------------------------------------------
__global__ __launch_bounds__(256) void SA_flash(
    const unsigned short* __restrict__ qws, const unsigned short* __restrict__ kws,
    const unsigned short* __restrict__ vws, const float* __restrict__ z,
    float* __restrict__ outp)
{
  __shared__ char Kt[64 * 80];     // 5120 B
  __shared__ char Vt[256 * 144];   // 36864 B
  const int bid = blockIdx.x;
  // XCD swizzle: consecutive 8 blocks (-> 8 XCDs) get batches 0,0,1,1,2,2,3,3
  const int b    = (bid >> 1) & 3;
  const int mblk = ((bid >> 3) << 1) | (bid & 1);
  const int m0 = mblk * 64;
  const int tid = threadIdx.x, lane = tid & 63, w = tid >> 6;
  const int g = lane >> 4, l15 = lane & 15;

  const unsigned short* qb = qws + (size_t)b * Nn * Dn;
  const unsigned short* kb = kws + (size_t)b * Nn * Dn;
  const unsigned short* vb = vws + (size_t)b * Cn * Nn;

  // Q fragment (B operand): col m = l15, k(d)-slots {4g+j, 16+4g+j}
  const int mw = m0 + 16 * w;
  short8 qf;
  {
    const char* qp = (const char*)qb + (size_t)(mw + l15) * 64 + 8 * g;
    ushort4 q0 = *(const ushort4*)qp;
    ushort4 q1 = *(const ushort4*)(qp + 32);
    qf[0]=(short)q0.x; qf[1]=(short)q0.y; qf[2]=(short)q0.z; qf[3]=(short)q0.w;
    qf[4]=(short)q1.x; qf[5]=(short)q1.y; qf[6]=(short)q1.z; qf[7]=(short)q1.w;
  }

  f32x4 acc[16];
#pragma unroll
  for (int i = 0; i < 16; ++i) { acc[i][0]=0.f; acc[i][1]=0.f; acc[i][2]=0.f; acc[i][3]=0.f; }
  float m_run = -__builtin_inff(), l_run = 0.f;

  const int knl = tid >> 2, kp = tid & 3;
  uint4 kreg; uint4 vreg[8];
  auto stage_load = [&](int kt) {
    const int n0 = kt * 64;
    kreg = *(const uint4*)((const char*)kb + (size_t)(n0 + knl) * 64 + kp * 16);
#pragma unroll
    for (int i = 0; i < 8; ++i) {
      int idx = i * 256 + tid, e = idx >> 3, ch = idx & 7;
      vreg[i] = *(const uint4*)((const char*)vb + (size_t)e * (Nn * 2) + (size_t)(n0 + ch * 8) * 2);
    }
  };
  stage_load(0);

  for (int kt = 0; kt < 64; ++kt) {
    { // regs -> LDS with k-map permutation
      int off1 = 32 * (kp & 1) + 8 * (kp >> 1);
      char* krow = Kt + (size_t)knl * 80;
      *(uint2*)(krow + off1)      = make_uint2(kreg.x, kreg.y);
      *(uint2*)(krow + off1 + 16) = make_uint2(kreg.z, kreg.w);
#pragma unroll
      for (int i = 0; i < 8; ++i) {
        int idx = i * 256 + tid, e = idx >> 3, ch = idx & 7;
        int p1 = 64 * (ch & 1) + 8 * (ch >> 1);
        char* vrow = Vt + (size_t)e * 144;
        *(uint2*)(vrow + p1)      = make_uint2(vreg[i].x, vreg[i].y);
        *(uint2*)(vrow + p1 + 32) = make_uint2(vreg[i].z, vreg[i].w);
      }
    }
    __syncthreads();
    if (kt < 63) stage_load(kt + 1);   // in flight during compute

    // ---- S^T tiles: rows n = 16t+4g+reg, col m = l15
    f32x4 s[4];
    const f32x4 zero4 = {0.f, 0.f, 0.f, 0.f};
#pragma unroll
    for (int t = 0; t < 4; ++t) {
      short8 kf = *(const short8*)(Kt + (size_t)(16*t + l15) * 80 + 16 * g);
      s[t] = __builtin_amdgcn_mfma_f32_16x16x32_bf16(kf, qf, zero4, 0, 0, 0);
    }
    // ---- online softmax over this tile's 64 keys (per query column m)
    float pm = s[0][0];
#pragma unroll
    for (int t = 0; t < 4; ++t)
#pragma unroll
      for (int r = 0; r < 4; ++r) pm = fmaxf(pm, s[t][r]);
    pm = fmaxf(pm, __shfl_xor(pm, 16, 64));
    pm = fmaxf(pm, __shfl_xor(pm, 32, 64));
    float mn = fmaxf(m_run, pm);
    float alpha = __expf(m_run - mn);
    float p[4][4]; float rs = 0.f;
#pragma unroll
    for (int t = 0; t < 4; ++t)
#pragma unroll
      for (int r = 0; r < 4; ++r) { float e = __expf(s[t][r] - mn); p[t][r] = e; rs += e; }
    rs += __shfl_xor(rs, 16, 64);
    rs += __shfl_xor(rs, 32, 64);
    l_run = l_run * alpha + rs;
    m_run = mn;
#pragma unroll
    for (int i = 0; i < 16; ++i) { acc[i][0]*=alpha; acc[i][1]*=alpha; acc[i][2]*=alpha; acc[i][3]*=alpha; }

    // ---- P^T -> B-frags, lane-local (zero shuffles): slot j = p[2c+(j>>2)][j&3]
    short8 pf[2];
#pragma unroll
    for (int c = 0; c < 2; ++c) {
      short8 t8;
      t8[0]=(short)f2bf(p[2*c][0]);   t8[1]=(short)f2bf(p[2*c][1]);
      t8[2]=(short)f2bf(p[2*c][2]);   t8[3]=(short)f2bf(p[2*c][3]);
      t8[4]=(short)f2bf(p[2*c+1][0]); t8[5]=(short)f2bf(p[2*c+1][1]);
      t8[6]=(short)f2bf(p[2*c+1][2]); t8[7]=(short)f2bf(p[2*c+1][3]);
      pf[c] = t8;
    }
    // ---- PV: out^T[e][m] += V[e][n] * P^T[n][m]
#pragma unroll
    for (int c = 0; c < 2; ++c)
#pragma unroll
      for (int et = 0; et < 16; ++et) {
        short8 vf = *(const short8*)(Vt + (size_t)(16*et + l15) * 144 + 32 * g + 16 * c);
        acc[et] = __builtin_amdgcn_mfma_f32_16x16x32_bf16(vf, pf[c], acc[et], 0, 0, 0);
      }
    __syncthreads();   // all reads done before next tile's LDS writes
  }

  // ---- epilogue: out = z + acc/l  (lane col m = l15, rows e = 16et+4g+r)
  float inv = 1.0f / l_run;
  const float* zb = z   + (size_t)b * Cn * Nn;
  float*       ob = outp + (size_t)b * Cn * Nn;
  const int mpos = mw + l15;
#pragma unroll
  for (int et = 0; et < 16; ++et)
#pragma unroll
    for (int r = 0; r < 4; ++r) {
      int e = 16*et + 4*g + r;
      size_t off = (size_t)e * Nn + mpos;
      ob[off] = zb[off] + acc[et][r] * inv;
    }
}

// ---------------------------------------------------------------------------
extern "C" void kernel_launch(void* const* d_in, const int* in_sizes, int n_in,
                              void* d_out, int out_size, void* d_ws, size_t ws_size,
                              hipStream_t stream) {
  (void)in_sizes; (void)n_in; (void)out_size; (void)ws_size;
  const float* z  = (const float*)d_in[0];
  const float* x  = (const float*)d_in[1];
  const float* y  = (const float*)d_in[2];
  const float* Wq = (const float*)d_in[3];
  const float* bq = (const float*)d_in[4];
  const float* Wk = (const float*)d_in[5];
  const float* bk = (const float*)d_in[6];
  const float* Wv = (const float*)d_in[7];
  const float* bv = (const float*)d_in[8];
  float* out = (float*)d_out;

  unsigned short* qws = (unsigned short*)d_ws;            // [4][4096][32] bf16
  unsigned short* kws = qws + (size_t)Bn * Nn * Dn;       // [4][4096][32] bf16
  unsigned short* vws = kws + (size_t)Bn * Nn * Dn;       // [4][256][4096] bf16

  SA_proj<<<640, 256, 0, stream>>>(x, y, z, Wq, bq, Wk, bk, Wv, bv, qws, kws, vws);
  SA_flash<<<256, 256, 0, stream>>>(qws, kws, vws, z, out);
}

// Round 3
// 207.987 us; speedup vs baseline: 1.0676x; 1.0676x over previous
//
#include <hip/hip_runtime.h>
#include <hip/hip_bf16.h>

#define Bn 4
#define Cn 256
#define Dn 32
#define Nn 4096

typedef __attribute__((ext_vector_type(8))) short short8;
typedef __attribute__((ext_vector_type(4))) float f32x4;

__device__ __forceinline__ unsigned short f2bf(float f) {
  union { __hip_bfloat16 h; unsigned short u; } c;
  c.h = __float2bfloat16(f);   // HW RNE cvt (compiler fuses pairs to v_cvt_pk_bf16_f32)
  return c.u;
}

// ---------------------------------------------------------------------------
// Q/K projection: out[b][n][d] (bf16, rows of 32 d = 64B) for q and k.
// Grid 512: bid<256 -> q (Wq,x), else k (Wk,y). Tile [32 d][64 n] per block.
// 4 waves x 16 n. Ping-pong register prefetch over the 8 c-chunks.
// k-map convention (everywhere): frag slot j (lane group g=lane>>4):
//   k = 4g+j (j<4), k = 16+4g+(j-4) (j>=4).
// ---------------------------------------------------------------------------
__global__ __launch_bounds__(256, 2) void SA_projqk(
    const float* __restrict__ x, const float* __restrict__ y,
    const float* __restrict__ Wq, const float* __restrict__ bq,
    const float* __restrict__ Wk, const float* __restrict__ bk,
    unsigned short* __restrict__ qws, unsigned short* __restrict__ kws)
{
  __shared__ char lds[64 * 80];
  const int bid = blockIdx.x, tid = threadIdx.x;
  const int lane = tid & 63, w = tid >> 6, g = lane >> 4, l15 = lane & 15;
  const int isq = bid < 256;
  const int t = bid & 255;
  const int b = t >> 6, n0 = (t & 63) << 6;
  const float* W    = isq ? Wq : Wk;
  const float* bias = isq ? bq : bk;
  const float* in   = (isq ? x : y) + (size_t)b * Cn * Nn;
  unsigned short* ob = (isq ? qws : kws) + (size_t)b * Nn * Dn;
  const int nw = n0 + 16 * w;

  f32x4 acc[2];
#pragma unroll
  for (int et = 0; et < 2; ++et) { acc[et][0]=0.f; acc[et][1]=0.f; acc[et][2]=0.f; acc[et][3]=0.f; }

  float4 A[2][2][2];      // [buf][et][half]
  float  Bv[2][8];        // [buf][slot]

  auto ld = [&](int ch, int s) {
#pragma unroll
    for (int et = 0; et < 2; ++et) {
      const float* wp = W + (size_t)(16*et + l15) * 256 + ch*32 + 4*g;
      A[s][et][0] = *(const float4*)wp;
      A[s][et][1] = *(const float4*)(wp + 16);
    }
    const float* ip  = in + (size_t)(ch*32 + 4*g) * Nn + nw + l15;
    const float* ip2 = ip + (size_t)16 * Nn;
#pragma unroll
    for (int j = 0; j < 4; ++j) { Bv[s][j] = ip[(size_t)j*Nn]; Bv[s][4+j] = ip2[(size_t)j*Nn]; }
  };
  auto comp = [&](int s) {
    short8 bf8;
#pragma unroll
    for (int j = 0; j < 8; ++j) bf8[j] = (short)f2bf(Bv[s][j]);
#pragma unroll
    for (int et = 0; et < 2; ++et) {
      short8 af;
      af[0]=(short)f2bf(A[s][et][0].x); af[1]=(short)f2bf(A[s][et][0].y);
      af[2]=(short)f2bf(A[s][et][0].z); af[3]=(short)f2bf(A[s][et][0].w);
      af[4]=(short)f2bf(A[s][et][1].x); af[5]=(short)f2bf(A[s][et][1].y);
      af[6]=(short)f2bf(A[s][et][1].z); af[7]=(short)f2bf(A[s][et][1].w);
      acc[et] = __builtin_amdgcn_mfma_f32_16x16x32_bf16(af, bf8, acc[et], 0, 0, 0);
    }
  };

  ld(0, 0);
#pragma unroll
  for (int ch = 0; ch < 8; ch += 2) {
    ld(ch + 1, 1);
    comp(0);
    if (ch < 6) ld(ch + 2, 0);
    comp(1);
  }

  // epilogue: +bias, repack [n][d] rows 80B, coalesced store
#pragma unroll
  for (int et = 0; et < 2; ++et) {
    int nl = 16*w + l15;
#pragma unroll
    for (int r = 0; r < 4; ++r) {
      int d = 16*et + 4*g + r;
      *(unsigned short*)(lds + (size_t)nl*80 + d*2) = f2bf(acc[et][r] + bias[d]);
    }
  }
  __syncthreads();
  {
    int nl = tid >> 2, c4 = tid & 3;
    *(uint4*)((char*)ob + (size_t)(n0 + nl)*64 + c4*16) = *(const uint4*)(lds + (size_t)nl*80 + c4*16);
  }
}

// ---------------------------------------------------------------------------
// V projection: out[b][e][n] bf16 ([B][C][N]). Grid 512: tile [64 e][128 n].
// b = bid>>7, e0 = ((bid>>5)&3)*64, n0 = (bid&31)*128. 4 waves x 32 n.
// ---------------------------------------------------------------------------
__global__ __launch_bounds__(256, 2) void SA_projv(
    const float* __restrict__ z,
    const float* __restrict__ Wv, const float* __restrict__ bv,
    unsigned short* __restrict__ vws)
{
  __shared__ char lds[64 * 272];
  const int bid = blockIdx.x, tid = threadIdx.x;
  const int lane = tid & 63, w = tid >> 6, g = lane >> 4, l15 = lane & 15;
  const int b = bid >> 7, e0 = ((bid >> 5) & 3) << 6, n0 = (bid & 31) << 7;
  const float* in = z + (size_t)b * Cn * Nn;
  const int nw = n0 + 32 * w;

  f32x4 acc[4][2];
#pragma unroll
  for (int et = 0; et < 4; ++et)
#pragma unroll
    for (int ns = 0; ns < 2; ++ns) { acc[et][ns][0]=0.f; acc[et][ns][1]=0.f; acc[et][ns][2]=0.f; acc[et][ns][3]=0.f; }

  float4 A[2][4][2];
  float  Bv2[2][2][8];

  auto ld = [&](int ch, int s) {
#pragma unroll
    for (int et = 0; et < 4; ++et) {
      const float* wp = Wv + (size_t)(e0 + 16*et + l15) * 256 + ch*32 + 4*g;
      A[s][et][0] = *(const float4*)wp;
      A[s][et][1] = *(const float4*)(wp + 16);
    }
#pragma unroll
    for (int ns = 0; ns < 2; ++ns) {
      const float* ip  = in + (size_t)(ch*32 + 4*g) * Nn + nw + 16*ns + l15;
      const float* ip2 = ip + (size_t)16 * Nn;
#pragma unroll
      for (int j = 0; j < 4; ++j) { Bv2[s][ns][j] = ip[(size_t)j*Nn]; Bv2[s][ns][4+j] = ip2[(size_t)j*Nn]; }
    }
  };
  auto comp = [&](int s) {
    short8 bf8[2];
#pragma unroll
    for (int ns = 0; ns < 2; ++ns)
#pragma unroll
      for (int j = 0; j < 8; ++j) bf8[ns][j] = (short)f2bf(Bv2[s][ns][j]);
#pragma unroll
    for (int et = 0; et < 4; ++et) {
      short8 af;
      af[0]=(short)f2bf(A[s][et][0].x); af[1]=(short)f2bf(A[s][et][0].y);
      af[2]=(short)f2bf(A[s][et][0].z); af[3]=(short)f2bf(A[s][et][0].w);
      af[4]=(short)f2bf(A[s][et][1].x); af[5]=(short)f2bf(A[s][et][1].y);
      af[6]=(short)f2bf(A[s][et][1].z); af[7]=(short)f2bf(A[s][et][1].w);
#pragma unroll
      for (int ns = 0; ns < 2; ++ns)
        acc[et][ns] = __builtin_amdgcn_mfma_f32_16x16x32_bf16(af, bf8[ns], acc[et][ns], 0, 0, 0);
    }
  };

  ld(0, 0);
#pragma unroll
  for (int ch = 0; ch < 8; ch += 2) {
    ld(ch + 1, 1);
    comp(0);
    if (ch < 6) ld(ch + 2, 0);
    comp(1);
  }

  // epilogue: +bias, repack [e][n] rows 272B (128 n * 2B + 16 pad), store
#pragma unroll
  for (int et = 0; et < 4; ++et) {
#pragma unroll
    for (int ns = 0; ns < 2; ++ns) {
      int nl = 32*w + 16*ns + l15;
#pragma unroll
      for (int r = 0; r < 4; ++r) {
        int el = 16*et + 4*g + r;
        *(unsigned short*)(lds + (size_t)el*272 + nl*2) = f2bf(acc[et][ns][r] + bv[e0 + el]);
      }
    }
  }
  __syncthreads();
#pragma unroll
  for (int i = 0; i < 4; ++i) {
    int idx = i*256 + tid, el = idx >> 4, c16 = idx & 15;
    *(uint4*)((char*)vws + (size_t)b*Cn*Nn*2 + (size_t)(e0 + el)*Nn*2 + (size_t)n0*2 + c16*16)
        = *(const uint4*)(lds + (size_t)el*272 + c16*16);
  }
}

// ---------------------------------------------------------------------------
// Flash attention + residual. Grid 256 x 512 threads (8 waves).
// Waves 0-3 = k-group 0 (even tiles), waves 4-7 = group 1 (odd tiles);
// each group has its own K/V LDS zone; exact (m,l,acc) combine at the end.
// Swapped QK^T so softmax is lane-local + 2 shfl. Defer-max (rescale only
// when a new max appears). setprio(1) around the PV MFMA cluster.
// ---------------------------------------------------------------------------
__global__ __launch_bounds__(512, 2) void SA_flash(
    const unsigned short* __restrict__ qws, const unsigned short* __restrict__ kws,
    const unsigned short* __restrict__ vws, const float* __restrict__ z,
    float* __restrict__ outp)
{
  __shared__ char lds[83968];          // 2 x (Kt 5120 + Vt 36864); reused for combine
  const int bid = blockIdx.x;
  const int b    = (bid >> 1) & 3;     // XCD pairs share a batch -> K/V L2-resident
  const int mblk = ((bid >> 3) << 1) | (bid & 1);
  const int m0 = mblk * 64;
  const int tid = threadIdx.x, lane = tid & 63;
  const int wv = tid >> 6, gg = wv >> 2, wq = wv & 3;
  const int g = lane >> 4, l15 = lane & 15;
  const int t2 = tid & 255;

  char* Kt = lds + gg * 41984;
  char* Vt = Kt + 5120;

  const unsigned short* qb = qws + (size_t)b * Nn * Dn;
  const unsigned short* kb = kws + (size_t)b * Nn * Dn;
  const unsigned short* vb = vws + (size_t)b * Cn * Nn;

  // Q fragment (B operand): col m = l15, k(d)-slots {4g+j, 16+4g+(j-4)}
  const int mw = m0 + 16 * wq;
  short8 qf;
  {
    const char* qp = (const char*)qb + (size_t)(mw + l15) * 64 + 8 * g;
    ushort4 q0 = *(const ushort4*)qp;
    ushort4 q1 = *(const ushort4*)(qp + 32);
    qf[0]=(short)q0.x; qf[1]=(short)q0.y; qf[2]=(short)q0.z; qf[3]=(short)q0.w;
    qf[4]=(short)q1.x; qf[5]=(short)q1.y; qf[6]=(short)q1.z; qf[7]=(short)q1.w;
  }

  f32x4 acc[16];
#pragma unroll
  for (int i = 0; i < 16; ++i) { acc[i][0]=0.f; acc[i][1]=0.f; acc[i][2]=0.f; acc[i][3]=0.f; }
  float m_run = -__builtin_inff(), l_run = 0.f;

  const int knl = t2 >> 2, kp = t2 & 3;
  uint4 kreg; uint4 vreg[8];
  auto stage_load = [&](int kt) {
    const int n0 = kt * 64;
    kreg = *(const uint4*)((const char*)kb + (size_t)(n0 + knl) * 64 + kp * 16);
#pragma unroll
    for (int i = 0; i < 8; ++i) {
      int idx = i * 256 + t2, e = idx >> 3, ch = idx & 7;
      vreg[i] = *(const uint4*)((const char*)vb + (size_t)e * (Nn * 2) + (size_t)(n0 + ch * 8) * 2);
    }
  };
  stage_load(gg);                      // first tile of my group

  for (int it = 0; it < 32; ++it) {
    { // regs -> LDS with k-map permutation (own group's zone)
      int off1 = 32 * (kp & 1) + 8 * (kp >> 1);
      char* krow = Kt + (size_t)knl * 80;
      *(uint2*)(krow + off1)      = make_uint2(kreg.x, kreg.y);
      *(uint2*)(krow + off1 + 16) = make_uint2(kreg.z, kreg.w);
#pragma unroll
      for (int i = 0; i < 8; ++i) {
        int idx = i * 256 + t2, e = idx >> 3, ch = idx & 7;
        int p1 = 64 * (ch & 1) + 8 * (ch >> 1);
        char* vrow = Vt + (size_t)e * 144;
        *(uint2*)(vrow + p1)      = make_uint2(vreg[i].x, vreg[i].y);
        *(uint2*)(vrow + p1 + 32) = make_uint2(vreg[i].z, vreg[i].w);
      }
    }
    __syncthreads();
    if (it < 31) stage_load(2 * (it + 1) + gg);   // in flight during compute

    // ---- S^T tiles: rows n = 16t+4g+reg, col m = l15
    f32x4 s[4];
    const f32x4 zero4 = {0.f, 0.f, 0.f, 0.f};
#pragma unroll
    for (int t = 0; t < 4; ++t) {
      short8 kf = *(const short8*)(Kt + (size_t)(16*t + l15) * 80 + 16 * g);
      s[t] = __builtin_amdgcn_mfma_f32_16x16x32_bf16(kf, qf, zero4, 0, 0, 0);
    }
    // ---- online softmax, defer-max: rescale only when a new max appears
    float pm = s[0][0];
#pragma unroll
    for (int t = 0; t < 4; ++t)
#pragma unroll
      for (int r = 0; r < 4; ++r) pm = fmaxf(pm, s[t][r]);
    pm = fmaxf(pm, __shfl_xor(pm, 16, 64));
    pm = fmaxf(pm, __shfl_xor(pm, 32, 64));
    if (__any(pm > m_run)) {
      float mn = fmaxf(m_run, pm);
      float alpha = __expf(m_run - mn);
      l_run *= alpha;
      m_run = mn;
#pragma unroll
      for (int i = 0; i < 16; ++i) { acc[i][0]*=alpha; acc[i][1]*=alpha; acc[i][2]*=alpha; acc[i][3]*=alpha; }
    }
    float p[4][4]; float rs = 0.f;
#pragma unroll
    for (int t = 0; t < 4; ++t)
#pragma unroll
      for (int r = 0; r < 4; ++r) { float e = __expf(s[t][r] - m_run); p[t][r] = e; rs += e; }
    rs += __shfl_xor(rs, 16, 64);
    rs += __shfl_xor(rs, 32, 64);
    l_run += rs;

    // ---- P^T -> B-frags, lane-local (zero shuffles)
    short8 pf[2];
#pragma unroll
    for (int c = 0; c < 2; ++c) {
      short8 t8;
      t8[0]=(short)f2bf(p[2*c][0]);   t8[1]=(short)f2bf(p[2*c][1]);
      t8[2]=(short)f2bf(p[2*c][2]);   t8[3]=(short)f2bf(p[2*c][3]);
      t8[4]=(short)f2bf(p[2*c+1][0]); t8[5]=(short)f2bf(p[2*c+1][1]);
      t8[6]=(short)f2bf(p[2*c+1][2]); t8[7]=(short)f2bf(p[2*c+1][3]);
      pf[c] = t8;
    }
    // ---- PV: out^T[e][m] += V[e][n] * P^T[n][m]
    __builtin_amdgcn_s_setprio(1);
#pragma unroll
    for (int c = 0; c < 2; ++c)
#pragma unroll
      for (int et = 0; et < 16; ++et) {
        short8 vf = *(const short8*)(Vt + (size_t)(16*et + l15) * 144 + 32 * g + 16 * c);
        acc[et] = __builtin_amdgcn_mfma_f32_16x16x32_bf16(vf, pf[c], acc[et], 0, 0, 0);
      }
    __builtin_amdgcn_s_setprio(0);
    __syncthreads();   // all reads done before next tile's LDS writes
  }

  // ---- cross-group combine (exact flash merge), then epilogue by group 0
  __syncthreads();
  float* mz = (float*)(lds + 73728);
  mz[tid] = m_run;
  __syncthreads();
  float m_oth = mz[tid ^ 256];
  float M  = fmaxf(m_run, m_oth);
  float al = __expf(m_run - M);
  float l_sc = l_run * al;
  float* lz = (float*)(lds + 75776);
  if (gg == 1) {
    char* rowp = lds + (size_t)t2 * 272;
#pragma unroll
    for (int i = 0; i < 16; ++i) {
      f32x4 v = acc[i];
      v[0]*=al; v[1]*=al; v[2]*=al; v[3]*=al;
      *(f32x4*)(rowp + i*16) = v;
    }
    lz[t2] = l_sc;
  }
  __syncthreads();
  if (gg == 0) {
    char* rowp = lds + (size_t)t2 * 272;
    float inv = 1.0f / (l_sc + lz[t2]);
    const float* zb = z    + (size_t)b * Cn * Nn;
    float*       ob = outp + (size_t)b * Cn * Nn;
    const int mpos = mw + l15;
#pragma unroll
    for (int et = 0; et < 16; ++et) {
      f32x4 o = *(const f32x4*)(rowp + et*16);
#pragma unroll
      for (int r = 0; r < 4; ++r) {
        int e = 16*et + 4*g + r;
        size_t off = (size_t)e * Nn + mpos;
        ob[off] = zb[off] + (acc[et][r]*al + o[r]) * inv;
      }
    }
  }
}

// ---------------------------------------------------------------------------
extern "C" void kernel_launch(void* const* d_in, const int* in_sizes, int n_in,
                              void* d_out, int out_size, void* d_ws, size_t ws_size,
                              hipStream_t stream) {
  (void)in_sizes; (void)n_in; (void)out_size; (void)ws_size;
  const float* z  = (const float*)d_in[0];
  const float* x  = (const float*)d_in[1];
  const float* y  = (const float*)d_in[2];
  const float* Wq = (const float*)d_in[3];
  const float* bq = (const float*)d_in[4];
  const float* Wk = (const float*)d_in[5];
  const float* bk = (const float*)d_in[6];
  const float* Wv = (const float*)d_in[7];
  const float* bv = (const float*)d_in[8];
  float* out = (float*)d_out;

  unsigned short* qws = (unsigned short*)d_ws;            // [4][4096][32] bf16
  unsigned short* kws = qws + (size_t)Bn * Nn * Dn;       // [4][4096][32] bf16
  unsigned short* vws = kws + (size_t)Bn * Nn * Dn;       // [4][256][4096] bf16

  SA_projqk<<<512, 256, 0, stream>>>(x, y, Wq, bq, Wk, bk, qws, kws);
  SA_projv <<<512, 256, 0, stream>>>(z, Wv, bv, vws);
  SA_flash <<<256, 512, 0, stream>>>(qws, kws, vws, z, out);
}

// Round 5
// 197.111 us; speedup vs baseline: 1.1265x; 1.0552x over previous
//
#include <hip/hip_runtime.h>
#include <hip/hip_bf16.h>

#define Bn 4
#define Cn 256
#define Dn 32
#define Nn 4096

typedef __attribute__((ext_vector_type(8))) short short8;
typedef __attribute__((ext_vector_type(4))) float f32x4;

__device__ __forceinline__ unsigned short f2bf(float f) {
  union { __hip_bfloat16 h; unsigned short u; } c;
  c.h = __float2bfloat16(f);   // HW RNE cvt (pairs fuse to v_cvt_pk_bf16_f32)
  return c.u;
}

// ============================================================================
// Fused projection kernel. Grid 256 = 4 b x 64 n-tiles (64 n each), 640 thr =
// 10 waves: wave0 -> q (Wq,x), wave1 -> k (Wk,y), waves 2-9 -> v (Wv,z; 32 e
// each). x/y/z tiles staged to LDS as [n][c] bf16 (rows 520 B) with coalesced
// 64B-per-4-lane float4 loads, 2 c-chunks of 128, T14 issue-early/write-late.
// W-chunk1 prefetch deliberately placed AFTER stage_wr(1) so sl* and wf are
// never co-live (peak ~140 VGPR < 168 cap for 3 waves/SIMD -> no spill).
// k-map (everywhere): frag slot j (lane group g): c = 4g+j (j<4), 16+4g+(j-4).
// Outputs: q,k as [B][N][32] bf16; v as [B][C][N] bf16.
// ============================================================================
__global__ __launch_bounds__(640, 1) void SA_proj2(
    const float* __restrict__ x, const float* __restrict__ y, const float* __restrict__ z,
    const float* __restrict__ Wq, const float* __restrict__ bq,
    const float* __restrict__ Wk, const float* __restrict__ bk,
    const float* __restrict__ Wv, const float* __restrict__ bv,
    unsigned short* __restrict__ qws, unsigned short* __restrict__ kws,
    unsigned short* __restrict__ vws)
{
  __shared__ char lds[3 * 33280];          // X,Y,Z tiles: [64 n][520 B] each
  const int bid = blockIdx.x, tid = threadIdx.x;
  const int lane = tid & 63, wv2 = tid >> 6;
  const int g = lane >> 4, l15 = lane & 15;
  const int b = bid >> 6, n0 = (bid & 63) << 6;

  const float* src0 = x + (size_t)b * Cn * Nn;
  const float* src1 = y + (size_t)b * Cn * Nn;
  const float* src2 = z + (size_t)b * Cn * Nn;

  const int isv = (wv2 >= 2);
  const float* W    = isv ? Wv : (wv2 == 0 ? Wq : Wk);
  const float* bias = isv ? bv : (wv2 == 0 ? bq : bk);
  const int e0w = isv ? ((wv2 - 2) << 5) : 0;
  const char* myT = lds + (isv ? 2 : wv2) * 33280;

  // staging role (threads 0..511): 4-lane group reads one full 256B row chunk;
  // lane fq covers n = fq*4 + i*16 + j  (n-term spreads LDS write banks).
  const int cl = tid >> 2, fq = tid & 3;

  f32x4 sl0[4], sl1[4], sl2[4];
  auto stage_ld = [&](int ck) {
    const size_t row = (size_t)(ck * 128 + cl) * Nn + n0 + fq * 4;
#pragma unroll
    for (int i = 0; i < 4; ++i) sl0[i] = *(const f32x4*)(src0 + row + i * 16);
#pragma unroll
    for (int i = 0; i < 4; ++i) sl1[i] = *(const f32x4*)(src1 + row + i * 16);
#pragma unroll
    for (int i = 0; i < 4; ++i) sl2[i] = *(const f32x4*)(src2 + row + i * 16);
  };
  auto stage_wr = [&](int ck) {
    const int cb = (ck * 128 + cl) * 2;
#pragma unroll
    for (int i = 0; i < 4; ++i)
#pragma unroll
      for (int j = 0; j < 4; ++j) {
        char* rp = lds + (size_t)(fq * 4 + i * 16 + j) * 520 + cb;
        *(unsigned short*)(rp)         = f2bf(sl0[i][j]);
        *(unsigned short*)(rp + 33280) = f2bf(sl1[i][j]);
        *(unsigned short*)(rp + 66560) = f2bf(sl2[i][j]);
      }
  };

  f32x4 wf[2][4][2];                       // W f32 staging [et][cc4][half]
  auto w_ld = [&](int ck) {
#pragma unroll
    for (int et = 0; et < 2; ++et) {
      const float* wp = W + (size_t)(e0w + 16 * et + l15) * 256 + ck * 128 + 4 * g;
#pragma unroll
      for (int cc = 0; cc < 4; ++cc) {
        wf[et][cc][0] = *(const f32x4*)(wp + cc * 32);
        wf[et][cc][1] = *(const f32x4*)(wp + cc * 32 + 16);
      }
    }
  };
  short8 af[2][4];
  auto w_cvt = [&]() {
#pragma unroll
    for (int et = 0; et < 2; ++et)
#pragma unroll
      for (int cc = 0; cc < 4; ++cc) {
        short8 t8;
#pragma unroll
        for (int j = 0; j < 4; ++j) {
          t8[j]     = (short)f2bf(wf[et][cc][0][j]);
          t8[4 + j] = (short)f2bf(wf[et][cc][1][j]);
        }
        af[et][cc] = t8;
      }
  };

  f32x4 acc[2][4];
#pragma unroll
  for (int et = 0; et < 2; ++et)
#pragma unroll
    for (int ns = 0; ns < 4; ++ns) { acc[et][ns][0]=0.f; acc[et][ns][1]=0.f; acc[et][ns][2]=0.f; acc[et][ns][3]=0.f; }

  auto compute = [&](int ck) {
#pragma unroll
    for (int cc = 0; cc < 4; ++cc) {
      const int cbyte = (ck * 128 + cc * 32 + 4 * g) * 2;
#pragma unroll
      for (int ns = 0; ns < 4; ++ns) {
        const char* rp = myT + (size_t)(16 * ns + l15) * 520 + cbyte;
        union { uint2 u[2]; short8 s; } bb;
        bb.u[0] = *(const uint2*)rp;
        bb.u[1] = *(const uint2*)(rp + 32);
#pragma unroll
        for (int et = 0; et < 2; ++et)
          acc[et][ns] = __builtin_amdgcn_mfma_f32_16x16x32_bf16(af[et][cc], bb.s, acc[et][ns], 0, 0, 0);
      }
    }
  };

  // ---- main sequence (T14 split; W-prefetch after sl* dies) ----
  if (tid < 512) stage_ld(0);
  w_ld(0);
  if (tid < 512) stage_wr(0);
  __syncthreads();                         // A: chunk0 tiles ready
  w_cvt();                                 // chunk0 W frags (wf freed)
  if (tid < 512) stage_ld(1);              // issue chunk1 loads early
  compute(0);                              // overlaps chunk1 global loads
  if (tid < 512) stage_wr(1);              // write-late (cols 128-255, disjoint)
  w_ld(1);                                 // W chunk1 (L2-hot) under barrier wait
  __syncthreads();                         // B: chunk1 ready
  w_cvt();
  compute(1);
  __syncthreads();                         // C: all frag reads done, LDS reusable

  // ---- epilogue: +bias, repack through LDS, coalesced stores ----
  float bvv[2][4];
#pragma unroll
  for (int et = 0; et < 2; ++et)
#pragma unroll
    for (int r = 0; r < 4; ++r) bvv[et][r] = bias[e0w + 16 * et + 4 * g + r];

  if (isv) {
    // v: [256 e][144 B] at lds+0
#pragma unroll
    for (int et = 0; et < 2; ++et)
#pragma unroll
      for (int ns = 0; ns < 4; ++ns)
#pragma unroll
        for (int r = 0; r < 4; ++r) {
          int e = e0w + 16 * et + 4 * g + r;
          int n = 16 * ns + l15;
          *(unsigned short*)(lds + (size_t)e * 144 + n * 2) = f2bf(acc[et][ns][r] + bvv[et][r]);
        }
  } else {
    // q/k: [64 n][80 B] at 66560 / 71680
    char* base = lds + (wv2 == 0 ? 66560 : 71680);
#pragma unroll
    for (int et = 0; et < 2; ++et)
#pragma unroll
      for (int ns = 0; ns < 4; ++ns)
#pragma unroll
        for (int r = 0; r < 4; ++r) {
          int d = 16 * et + 4 * g + r;
          int n = 16 * ns + l15;
          *(unsigned short*)(base + (size_t)n * 80 + d * 2) = f2bf(acc[et][ns][r] + bvv[et][r]);
        }
  }
  __syncthreads();                         // D: repack visible

  if (tid < 512) {                         // v store: [B][C][N], 128B rows
    const int el = tid >> 1, half = tid & 1;
    char* gb = (char*)vws + (size_t)b * Cn * Nn * 2 + (size_t)el * Nn * 2 + (size_t)n0 * 2 + half * 64;
    const char* lb = lds + (size_t)el * 144 + half * 64;
#pragma unroll
    for (int i = 0; i < 4; ++i)
      *(uint4*)(gb + i * 16) = *(const uint4*)(lb + i * 16);
  }
  if (wv2 < 2) {                           // q/k store: contiguous 4KB block
    unsigned short* ob = (wv2 == 0 ? qws : kws) + (size_t)b * Nn * Dn;
    const char* base = lds + (wv2 == 0 ? 66560 : 71680);
#pragma unroll
    for (int i = 0; i < 4; ++i) {
      int flat = 64 * i + lane;
      *(uint4*)((char*)ob + (size_t)n0 * 64 + flat * 16)
          = *(const uint4*)(base + (size_t)(flat >> 2) * 80 + (flat & 3) * 16);
    }
  }
}

// ---------------------------------------------------------------------------
// Flash attention + residual. UNCHANGED from round 3 (known-good, 93.6 us).
// ---------------------------------------------------------------------------
__global__ __launch_bounds__(512, 2) void SA_flash(
    const unsigned short* __restrict__ qws, const unsigned short* __restrict__ kws,
    const unsigned short* __restrict__ vws, const float* __restrict__ z,
    float* __restrict__ outp)
{
  __shared__ char lds[83968];          // 2 x (Kt 5120 + Vt 36864); reused for combine
  const int bid = blockIdx.x;
  const int b    = (bid >> 1) & 3;     // XCD pairs share a batch -> K/V L2-resident
  const int mblk = ((bid >> 3) << 1) | (bid & 1);
  const int m0 = mblk * 64;
  const int tid = threadIdx.x, lane = tid & 63;
  const int wv = tid >> 6, gg = wv >> 2, wq = wv & 3;
  const int g = lane >> 4, l15 = lane & 15;
  const int t2 = tid & 255;

  char* Kt = lds + gg * 41984;
  char* Vt = Kt + 5120;

  const unsigned short* qb = qws + (size_t)b * Nn * Dn;
  const unsigned short* kb = kws + (size_t)b * Nn * Dn;
  const unsigned short* vb = vws + (size_t)b * Cn * Nn;

  const int mw = m0 + 16 * wq;
  short8 qf;
  {
    const char* qp = (const char*)qb + (size_t)(mw + l15) * 64 + 8 * g;
    ushort4 q0 = *(const ushort4*)qp;
    ushort4 q1 = *(const ushort4*)(qp + 32);
    qf[0]=(short)q0.x; qf[1]=(short)q0.y; qf[2]=(short)q0.z; qf[3]=(short)q0.w;
    qf[4]=(short)q1.x; qf[5]=(short)q1.y; qf[6]=(short)q1.z; qf[7]=(short)q1.w;
  }

  f32x4 acc[16];
#pragma unroll
  for (int i = 0; i < 16; ++i) { acc[i][0]=0.f; acc[i][1]=0.f; acc[i][2]=0.f; acc[i][3]=0.f; }
  float m_run = -__builtin_inff(), l_run = 0.f;

  const int knl = t2 >> 2, kp = t2 & 3;
  uint4 kreg; uint4 vreg[8];
  auto stage_load = [&](int kt) {
    const int n0 = kt * 64;
    kreg = *(const uint4*)((const char*)kb + (size_t)(n0 + knl) * 64 + kp * 16);
#pragma unroll
    for (int i = 0; i < 8; ++i) {
      int idx = i * 256 + t2, e = idx >> 3, ch = idx & 7;
      vreg[i] = *(const uint4*)((const char*)vb + (size_t)e * (Nn * 2) + (size_t)(n0 + ch * 8) * 2);
    }
  };
  stage_load(gg);

  for (int it = 0; it < 32; ++it) {
    {
      int off1 = 32 * (kp & 1) + 8 * (kp >> 1);
      char* krow = Kt + (size_t)knl * 80;
      *(uint2*)(krow + off1)      = make_uint2(kreg.x, kreg.y);
      *(uint2*)(krow + off1 + 16) = make_uint2(kreg.z, kreg.w);
#pragma unroll
      for (int i = 0; i < 8; ++i) {
        int idx = i * 256 + t2, e = idx >> 3, ch = idx & 7;
        int p1 = 64 * (ch & 1) + 8 * (ch >> 1);
        char* vrow = Vt + (size_t)e * 144;
        *(uint2*)(vrow + p1)      = make_uint2(vreg[i].x, vreg[i].y);
        *(uint2*)(vrow + p1 + 32) = make_uint2(vreg[i].z, vreg[i].w);
      }
    }
    __syncthreads();
    if (it < 31) stage_load(2 * (it + 1) + gg);

    f32x4 s[4];
    const f32x4 zero4 = {0.f, 0.f, 0.f, 0.f};
#pragma unroll
    for (int t = 0; t < 4; ++t) {
      short8 kf = *(const short8*)(Kt + (size_t)(16*t + l15) * 80 + 16 * g);
      s[t] = __builtin_amdgcn_mfma_f32_16x16x32_bf16(kf, qf, zero4, 0, 0, 0);
    }
    float pm = s[0][0];
#pragma unroll
    for (int t = 0; t < 4; ++t)
#pragma unroll
      for (int r = 0; r < 4; ++r) pm = fmaxf(pm, s[t][r]);
    pm = fmaxf(pm, __shfl_xor(pm, 16, 64));
    pm = fmaxf(pm, __shfl_xor(pm, 32, 64));
    if (__any(pm > m_run)) {
      float mn = fmaxf(m_run, pm);
      float alpha = __expf(m_run - mn);
      l_run *= alpha;
      m_run = mn;
#pragma unroll
      for (int i = 0; i < 16; ++i) { acc[i][0]*=alpha; acc[i][1]*=alpha; acc[i][2]*=alpha; acc[i][3]*=alpha; }
    }
    float p[4][4]; float rs = 0.f;
#pragma unroll
    for (int t = 0; t < 4; ++t)
#pragma unroll
      for (int r = 0; r < 4; ++r) { float e = __expf(s[t][r] - m_run); p[t][r] = e; rs += e; }
    rs += __shfl_xor(rs, 16, 64);
    rs += __shfl_xor(rs, 32, 64);
    l_run += rs;

    short8 pf[2];
#pragma unroll
    for (int c = 0; c < 2; ++c) {
      short8 t8;
      t8[0]=(short)f2bf(p[2*c][0]);   t8[1]=(short)f2bf(p[2*c][1]);
      t8[2]=(short)f2bf(p[2*c][2]);   t8[3]=(short)f2bf(p[2*c][3]);
      t8[4]=(short)f2bf(p[2*c+1][0]); t8[5]=(short)f2bf(p[2*c+1][1]);
      t8[6]=(short)f2bf(p[2*c+1][2]); t8[7]=(short)f2bf(p[2*c+1][3]);
      pf[c] = t8;
    }
    __builtin_amdgcn_s_setprio(1);
#pragma unroll
    for (int c = 0; c < 2; ++c)
#pragma unroll
      for (int et = 0; et < 16; ++et) {
        short8 vf = *(const short8*)(Vt + (size_t)(16*et + l15) * 144 + 32 * g + 16 * c);
        acc[et] = __builtin_amdgcn_mfma_f32_16x16x32_bf16(vf, pf[c], acc[et], 0, 0, 0);
      }
    __builtin_amdgcn_s_setprio(0);
    __syncthreads();
  }

  __syncthreads();
  float* mz = (float*)(lds + 73728);
  mz[tid] = m_run;
  __syncthreads();
  float m_oth = mz[tid ^ 256];
  float M  = fmaxf(m_run, m_oth);
  float al = __expf(m_run - M);
  float l_sc = l_run * al;
  float* lz = (float*)(lds + 75776);
  if (gg == 1) {
    char* rowp = lds + (size_t)t2 * 272;
#pragma unroll
    for (int i = 0; i < 16; ++i) {
      f32x4 v = acc[i];
      v[0]*=al; v[1]*=al; v[2]*=al; v[3]*=al;
      *(f32x4*)(rowp + i*16) = v;
    }
    lz[t2] = l_sc;
  }
  __syncthreads();
  if (gg == 0) {
    char* rowp = lds + (size_t)t2 * 272;
    float inv = 1.0f / (l_sc + lz[t2]);
    const float* zb = z    + (size_t)b * Cn * Nn;
    float*       ob = outp + (size_t)b * Cn * Nn;
    const int mpos = mw + l15;
#pragma unroll
    for (int et = 0; et < 16; ++et) {
      f32x4 o = *(const f32x4*)(rowp + et*16);
#pragma unroll
      for (int r = 0; r < 4; ++r) {
        int e = 16*et + 4*g + r;
        size_t off = (size_t)e * Nn + mpos;
        ob[off] = zb[off] + (acc[et][r]*al + o[r]) * inv;
      }
    }
  }
}

// ---------------------------------------------------------------------------
extern "C" void kernel_launch(void* const* d_in, const int* in_sizes, int n_in,
                              void* d_out, int out_size, void* d_ws, size_t ws_size,
                              hipStream_t stream) {
  (void)in_sizes; (void)n_in; (void)out_size; (void)ws_size;
  const float* z  = (const float*)d_in[0];
  const float* x  = (const float*)d_in[1];
  const float* y  = (const float*)d_in[2];
  const float* Wq = (const float*)d_in[3];
  const float* bq = (const float*)d_in[4];
  const float* Wk = (const float*)d_in[5];
  const float* bk = (const float*)d_in[6];
  const float* Wv = (const float*)d_in[7];
  const float* bv = (const float*)d_in[8];
  float* out = (float*)d_out;

  unsigned short* qws = (unsigned short*)d_ws;            // [4][4096][32] bf16
  unsigned short* kws = qws + (size_t)Bn * Nn * Dn;       // [4][4096][32] bf16
  unsigned short* vws = kws + (size_t)Bn * Nn * Dn;       // [4][256][4096] bf16

  SA_proj2<<<256, 640, 0, stream>>>(x, y, z, Wq, bq, Wk, bk, Wv, bv, qws, kws, vws);
  SA_flash<<<256, 512, 0, stream>>>(qws, kws, vws, z, out);
}

// Round 6
// 172.374 us; speedup vs baseline: 1.2882x; 1.1435x over previous
//
#include <hip/hip_runtime.h>
#include <hip/hip_bf16.h>

#define Bn 4
#define Cn 256
#define Dn 32
#define Nn 4096

typedef __attribute__((ext_vector_type(8))) short short8;
typedef __attribute__((ext_vector_type(4))) float f32x4;

union U16 { uint4 u; short8 s; };

__device__ __forceinline__ unsigned short f2bf(float f) {
  union { __hip_bfloat16 h; unsigned short u; } c;
  c.h = __float2bfloat16(f);   // HW RNE cvt (pairs fuse to v_cvt_pk_bf16_f32)
  return c.u;
}

// ============================================================================
// Fused projection kernel (structure measured-good in r5; epilogue now emits
// MFMA-FRAG-ORDERED layouts so flash reads K/V fragments straight from L2).
//   qws: [B][N][32] bf16 rows (unchanged — flash Q load is per-q-row).
//   kws: [B][kt=64][t=4][chunk=64][16B]  chunk = g*16 + row(n&15); bytes
//        within chunk: et*8 + r*2 for d = 16et+4g+r (the k-map d-perm).
//   vws: [B][kt=64][wq=4][frag=8][chunk=64][16B]  frag = et*2+ks,
//        chunk = (n-group)*16 + (e&15); bytes: (ns&1)*8 + (n&3)*2.
// k-map (everywhere): frag slot j (lane group g): k = 4g+j (j<4), 16+4g+(j-4).
// ============================================================================
__global__ __launch_bounds__(640, 1) void SA_proj2(
    const float* __restrict__ x, const float* __restrict__ y, const float* __restrict__ z,
    const float* __restrict__ Wq, const float* __restrict__ bq,
    const float* __restrict__ Wk, const float* __restrict__ bk,
    const float* __restrict__ Wv, const float* __restrict__ bv,
    unsigned short* __restrict__ qws, unsigned short* __restrict__ kws,
    unsigned short* __restrict__ vws)
{
  __shared__ char lds[3 * 33280];          // X,Y,Z tiles: [64 n][520 B] each
  const int bid = blockIdx.x, tid = threadIdx.x;
  const int lane = tid & 63, wv2 = tid >> 6;
  const int g = lane >> 4, l15 = lane & 15;
  const int b = bid >> 6, n0 = (bid & 63) << 6;
  const int kt = n0 >> 6;

  const float* src0 = x + (size_t)b * Cn * Nn;
  const float* src1 = y + (size_t)b * Cn * Nn;
  const float* src2 = z + (size_t)b * Cn * Nn;

  const int isv = (wv2 >= 2);
  const float* W    = isv ? Wv : (wv2 == 0 ? Wq : Wk);
  const float* bias = isv ? bv : (wv2 == 0 ? bq : bk);
  const int e0w = isv ? ((wv2 - 2) << 5) : 0;
  const char* myT = lds + (isv ? 2 : wv2) * 33280;

  const int cl = tid >> 2, fq = tid & 3;

  f32x4 sl0[4], sl1[4], sl2[4];
  auto stage_ld = [&](int ck) {
    const size_t row = (size_t)(ck * 128 + cl) * Nn + n0 + fq * 4;
#pragma unroll
    for (int i = 0; i < 4; ++i) sl0[i] = *(const f32x4*)(src0 + row + i * 16);
#pragma unroll
    for (int i = 0; i < 4; ++i) sl1[i] = *(const f32x4*)(src1 + row + i * 16);
#pragma unroll
    for (int i = 0; i < 4; ++i) sl2[i] = *(const f32x4*)(src2 + row + i * 16);
  };
  auto stage_wr = [&](int ck) {
    const int cb = (ck * 128 + cl) * 2;
#pragma unroll
    for (int i = 0; i < 4; ++i)
#pragma unroll
      for (int j = 0; j < 4; ++j) {
        char* rp = lds + (size_t)(fq * 4 + i * 16 + j) * 520 + cb;
        *(unsigned short*)(rp)         = f2bf(sl0[i][j]);
        *(unsigned short*)(rp + 33280) = f2bf(sl1[i][j]);
        *(unsigned short*)(rp + 66560) = f2bf(sl2[i][j]);
      }
  };

  f32x4 wf[2][4][2];
  auto w_ld = [&](int ck) {
#pragma unroll
    for (int et = 0; et < 2; ++et) {
      const float* wp = W + (size_t)(e0w + 16 * et + l15) * 256 + ck * 128 + 4 * g;
#pragma unroll
      for (int cc = 0; cc < 4; ++cc) {
        wf[et][cc][0] = *(const f32x4*)(wp + cc * 32);
        wf[et][cc][1] = *(const f32x4*)(wp + cc * 32 + 16);
      }
    }
  };
  short8 af[2][4];
  auto w_cvt = [&]() {
#pragma unroll
    for (int et = 0; et < 2; ++et)
#pragma unroll
      for (int cc = 0; cc < 4; ++cc) {
        short8 t8;
#pragma unroll
        for (int j = 0; j < 4; ++j) {
          t8[j]     = (short)f2bf(wf[et][cc][0][j]);
          t8[4 + j] = (short)f2bf(wf[et][cc][1][j]);
        }
        af[et][cc] = t8;
      }
  };

  f32x4 acc[2][4];
#pragma unroll
  for (int et = 0; et < 2; ++et)
#pragma unroll
    for (int ns = 0; ns < 4; ++ns) { acc[et][ns][0]=0.f; acc[et][ns][1]=0.f; acc[et][ns][2]=0.f; acc[et][ns][3]=0.f; }

  auto compute = [&](int ck) {
#pragma unroll
    for (int cc = 0; cc < 4; ++cc) {
      const int cbyte = (ck * 128 + cc * 32 + 4 * g) * 2;
#pragma unroll
      for (int ns = 0; ns < 4; ++ns) {
        const char* rp = myT + (size_t)(16 * ns + l15) * 520 + cbyte;
        U16 bb;
        bb.u.x = *(const unsigned*)rp;        bb.u.y = *(const unsigned*)(rp + 4);
        bb.u.z = *(const unsigned*)(rp + 32); bb.u.w = *(const unsigned*)(rp + 36);
#pragma unroll
        for (int et = 0; et < 2; ++et)
          acc[et][ns] = __builtin_amdgcn_mfma_f32_16x16x32_bf16(af[et][cc], bb.s, acc[et][ns], 0, 0, 0);
      }
    }
  };

  if (tid < 512) stage_ld(0);
  w_ld(0);
  if (tid < 512) stage_wr(0);
  __syncthreads();                         // A: chunk0 tiles ready
  w_cvt();
  if (tid < 512) stage_ld(1);
  compute(0);
  if (tid < 512) stage_wr(1);
  w_ld(1);
  __syncthreads();                         // B: chunk1 ready
  w_cvt();
  compute(1);
  __syncthreads();                         // C: LDS reusable

  // ---- epilogue: +bias, repack to FRAG layouts, coalesced stores ----
  float bvv[2][4];
#pragma unroll
  for (int et = 0; et < 2; ++et)
#pragma unroll
    for (int r = 0; r < 4; ++r) bvv[et][r] = bias[e0w + 16 * et + 4 * g + r];

  if (isv) {
    // v frag region [0, 32768): [wq 4][frag 8][chunk 64][16B]
    const int vw = wv2 - 2, Wt = vw >> 1, w1 = vw & 1;
#pragma unroll
    for (int et = 0; et < 2; ++et)
#pragma unroll
      for (int ns = 0; ns < 4; ++ns)
#pragma unroll
        for (int r = 0; r < 4; ++r) {
          int byte = Wt * 8192 + (((2 * w1 + et) << 1) + (ns >> 1)) * 1024
                   + ((l15 >> 2) * 16 + 4 * g + r) * 16 + (ns & 1) * 8 + (l15 & 3) * 2;
          *(unsigned short*)(lds + byte) = f2bf(acc[et][ns][r] + bvv[et][r]);
        }
  } else if (wv2 == 0) {
    // q: [64 n][80 B] at 66560 (unchanged layout)
    char* base = lds + 66560;
#pragma unroll
    for (int et = 0; et < 2; ++et)
#pragma unroll
      for (int ns = 0; ns < 4; ++ns)
#pragma unroll
        for (int r = 0; r < 4; ++r) {
          int d = 16 * et + 4 * g + r;
          int n = 16 * ns + l15;
          *(unsigned short*)(base + (size_t)n * 80 + d * 2) = f2bf(acc[et][ns][r] + bvv[et][r]);
        }
  } else {
    // k frag region 4KB at 71680: [t 4][chunk 64][16B], chunk = g*16 + l15
    char* base = lds + 71680;
#pragma unroll
    for (int et = 0; et < 2; ++et)
#pragma unroll
      for (int ns = 0; ns < 4; ++ns)
#pragma unroll
        for (int r = 0; r < 4; ++r) {
          int pos = ns * 1024 + g * 256 + l15 * 16 + et * 8 + r * 2;
          *(unsigned short*)(base + pos) = f2bf(acc[et][ns][r] + bvv[et][r]);
        }
  }
  __syncthreads();                         // D: repack visible

  if (tid < 512) {                         // v store: 32 KB contiguous
    char* gb = (char*)vws + (size_t)b * Cn * Nn * 2 + (size_t)kt * 32768 + tid * 64;
    const char* lb = lds + tid * 64;
#pragma unroll
    for (int i = 0; i < 4; ++i)
      *(uint4*)(gb + i * 16) = *(const uint4*)(lb + i * 16);
  }
  if (wv2 == 0) {                          // q store: [B][N][32] (unchanged)
    unsigned short* ob = qws + (size_t)b * Nn * Dn;
#pragma unroll
    for (int i = 0; i < 4; ++i) {
      int flat = 64 * i + lane;
      *(uint4*)((char*)ob + (size_t)n0 * 64 + flat * 16)
          = *(const uint4*)(lds + 66560 + (size_t)(flat >> 2) * 80 + (flat & 3) * 16);
    }
  } else if (wv2 == 1) {                   // k store: 4 KB frag block
    char* ob = (char*)kws + (size_t)b * Nn * Dn * 2 + (size_t)kt * 4096;
#pragma unroll
    for (int i = 0; i < 4; ++i) {
      int flat = 64 * i + lane;
      *(uint4*)(ob + flat * 16) = *(const uint4*)(lds + 71680 + flat * 16);
    }
  }
}

// ============================================================================
// Flash attention v3 + residual. Grid 256 x 512 thr (8 waves = 2 k-groups x 4).
// K/V fragments load GLOBAL->REG (frag-ordered ws layouts, L2-resident,
// prefetched 1 tile ahead) — no K/V LDS staging at all. Each wave: softmax
// owns 16 q (swapped QK^T, lane-local + 2 shfl, exact batched-max rescale);
// PV owns 64 e x all 64 q; P crosses waves via an 8 KB frag-ordered LDS
// buffer (2 b128 writes + 8 b128 reads per wave-iter, conflict-free).
// Exact (m,l,acc) cross-group combine at the end.
// ============================================================================
__global__ __launch_bounds__(512, 2) void SA_flash(
    const unsigned short* __restrict__ qws, const unsigned short* __restrict__ kws,
    const unsigned short* __restrict__ vws, const float* __restrict__ z,
    float* __restrict__ outp)
{
  __shared__ char lds[68608];
  // [0,16384): P frags (group g at g*8192). [0,66560): combine (epilogue only).
  // 66560: m_arr f32[2][64]; 67072: l_arr; 67584: a_arr; 68096: flags u32[2][4].
  float*    m_arr = (float*)(lds + 66560);
  float*    l_arr = (float*)(lds + 67072);
  float*    a_arr = (float*)(lds + 67584);
  unsigned* f_arr = (unsigned*)(lds + 68096);

  const int bid = blockIdx.x;
  const int b    = (bid >> 1) & 3;     // XCD pairs share a batch -> K/V L2-resident
  const int mblk = ((bid >> 3) << 1) | (bid & 1);
  const int m0 = mblk * 64;
  const int tid = threadIdx.x, lane = tid & 63;
  const int wv = tid >> 6, gg = wv >> 2, wq = wv & 3;
  const int g = lane >> 4, l15 = lane & 15;

  char* Pg = lds + gg * 8192;

  const unsigned short* qb = qws + (size_t)b * Nn * Dn;
  const char* kb = (const char*)kws + (size_t)b * Nn * Dn * 2;
  const char* vb = (const char*)vws + (size_t)b * Cn * Nn * 2;

  // Q fragment (B operand): col q = 16wq + l15, k(d)-slots per k-map
  const int mw = m0 + 16 * wq;
  short8 qf;
  {
    const char* qp = (const char*)qb + (size_t)(mw + l15) * 64 + 8 * g;
    ushort4 q0 = *(const ushort4*)qp;
    ushort4 q1 = *(const ushort4*)(qp + 32);
    qf[0]=(short)q0.x; qf[1]=(short)q0.y; qf[2]=(short)q0.z; qf[3]=(short)q0.w;
    qf[4]=(short)q1.x; qf[5]=(short)q1.y; qf[6]=(short)q1.z; qf[7]=(short)q1.w;
  }

  f32x4 acc[4][4];                      // [et][qt]: e = 64wq+16et+4g+r, q = 16qt+l15
#pragma unroll
  for (int et = 0; et < 4; ++et)
#pragma unroll
    for (int qt = 0; qt < 4; ++qt) { acc[et][qt][0]=0.f; acc[et][qt][1]=0.f; acc[et][qt][2]=0.f; acc[et][qt][3]=0.f; }
  float m_run = -__builtin_inff(), l_run = 0.f;

  uint4 kfr[4], vfr[8];
  auto k_ld = [&](int t4) {
    const char* p = kb + (size_t)t4 * 4096 + lane * 16;
#pragma unroll
    for (int t = 0; t < 4; ++t) kfr[t] = *(const uint4*)(p + t * 1024);
  };
  auto v_ld = [&](int t4) {
    const char* p = vb + (size_t)t4 * 32768 + wq * 8192 + lane * 16;
#pragma unroll
    for (int f = 0; f < 8; ++f) vfr[f] = *(const uint4*)(p + f * 1024);
  };
  k_ld(gg); v_ld(gg);

  for (int it = 0; it < 32; ++it) {
    // ---- S^T tiles from register K frags: rows n = 16t+4g+r, col q = l15
    f32x4 s[4];
    const f32x4 zero4 = {0.f, 0.f, 0.f, 0.f};
#pragma unroll
    for (int t = 0; t < 4; ++t) {
      U16 ku; ku.u = kfr[t];
      s[t] = __builtin_amdgcn_mfma_f32_16x16x32_bf16(ku.s, qf, zero4, 0, 0, 0);
    }
    if (it < 31) k_ld(2 * (it + 1) + gg);   // prefetch next K (regs free post-issue)

    // ---- softmax for this wave's 16 q (exact, batched-max update)
    float pm = s[0][0];
#pragma unroll
    for (int t = 0; t < 4; ++t)
#pragma unroll
      for (int r = 0; r < 4; ++r) pm = fmaxf(pm, s[t][r]);
    pm = fmaxf(pm, __shfl_xor(pm, 16, 64));
    pm = fmaxf(pm, __shfl_xor(pm, 32, 64));
    int trig = __any(pm > m_run);
    float alpha = 1.0f;
    if (trig) {
      float mn = fmaxf(m_run, pm);
      alpha = __expf(m_run - mn);
      l_run *= alpha;
      m_run = mn;
    }
    float p[4][4]; float rs = 0.f;
#pragma unroll
    for (int t = 0; t < 4; ++t)
#pragma unroll
      for (int r = 0; r < 4; ++r) { float e = __expf(s[t][r] - m_run); p[t][r] = e; rs += e; }
    rs += __shfl_xor(rs, 16, 64);
    rs += __shfl_xor(rs, 32, 64);
    l_run += rs;

    // ---- P^T frags (lane-local), write to frag-ordered P LDS
    short8 pf[2];
#pragma unroll
    for (int c = 0; c < 2; ++c) {
      short8 t8;
      t8[0]=(short)f2bf(p[2*c][0]);   t8[1]=(short)f2bf(p[2*c][1]);
      t8[2]=(short)f2bf(p[2*c][2]);   t8[3]=(short)f2bf(p[2*c][3]);
      t8[4]=(short)f2bf(p[2*c+1][0]); t8[5]=(short)f2bf(p[2*c+1][1]);
      t8[6]=(short)f2bf(p[2*c+1][2]); t8[7]=(short)f2bf(p[2*c+1][3]);
      pf[c] = t8;
    }
    *(short8*)(Pg + (wq * 2 + 0) * 1024 + lane * 16) = pf[0];
    *(short8*)(Pg + (wq * 2 + 1) * 1024 + lane * 16) = pf[1];
    if (lane < 16) a_arr[gg * 64 + 16 * wq + lane] = alpha;
    if (lane == 0) f_arr[gg * 4 + wq] = (unsigned)trig;
    __syncthreads();                      // P + alpha visible

    // ---- rescale acc (uniform branch; rare after warmup)
    {
      uint4 fl = *(const uint4*)(f_arr + gg * 4);
      if (fl.x | fl.y | fl.z | fl.w) {
        float al4[4];
#pragma unroll
        for (int qt = 0; qt < 4; ++qt) al4[qt] = a_arr[gg * 64 + 16 * qt + l15];
#pragma unroll
        for (int et = 0; et < 4; ++et)
#pragma unroll
          for (int qt = 0; qt < 4; ++qt) {
            acc[et][qt][0]*=al4[qt]; acc[et][qt][1]*=al4[qt];
            acc[et][qt][2]*=al4[qt]; acc[et][qt][3]*=al4[qt];
          }
      }
    }

    // ---- PV: out^T[e][q] += V[e][n] * P^T[n][q]  (V from regs, P from LDS)
    __builtin_amdgcn_s_setprio(1);
#pragma unroll
    for (int qt = 0; qt < 4; ++qt) {
#pragma unroll
      for (int ks = 0; ks < 2; ++ks) {
        short8 pfr = *(const short8*)(Pg + (qt * 2 + ks) * 1024 + lane * 16);
#pragma unroll
        for (int et = 0; et < 4; ++et) {
          U16 vu; vu.u = vfr[et * 2 + ks];
          acc[et][qt] = __builtin_amdgcn_mfma_f32_16x16x32_bf16(vu.s, pfr, acc[et][qt], 0, 0, 0);
        }
      }
    }
    __builtin_amdgcn_s_setprio(0);
    if (it < 31) v_ld(2 * (it + 1) + gg);   // prefetch next V
    __syncthreads();                      // P reads done before next write
  }

  // ---- exact cross-group combine, then epilogue by group 0
  if (lane < 16) {
    m_arr[gg * 64 + 16 * wq + lane] = m_run;
    l_arr[gg * 64 + 16 * wq + lane] = l_run;
  }
  __syncthreads();
  float fmy[4], inv[4];
#pragma unroll
  for (int qt = 0; qt < 4; ++qt) {
    int q = 16 * qt + l15;
    float mv0 = m_arr[q], mv1 = m_arr[64 + q];
    float lv0 = l_arr[q], lv1 = l_arr[64 + q];
    float M = fmaxf(mv0, mv1);
    float f0 = __expf(mv0 - M), f1 = __expf(mv1 - M);
    inv[qt] = 1.0f / (lv0 * f0 + lv1 * f1);
    fmy[qt] = gg ? f1 : f0;
  }
#pragma unroll
  for (int et = 0; et < 4; ++et)
#pragma unroll
    for (int qt = 0; qt < 4; ++qt) {
      acc[et][qt][0]*=fmy[qt]; acc[et][qt][1]*=fmy[qt];
      acc[et][qt][2]*=fmy[qt]; acc[et][qt][3]*=fmy[qt];
    }
  if (gg == 1) {
#pragma unroll
    for (int et = 0; et < 4; ++et)
#pragma unroll
      for (int qt = 0; qt < 4; ++qt)
        *(f32x4*)(lds + (size_t)(16 * qt + l15) * 1040 + (64 * wq + 16 * et + 4 * g) * 4) = acc[et][qt];
  }
  __syncthreads();
  if (gg == 0) {
    const float* zb = z    + (size_t)b * Cn * Nn;
    float*       ob = outp + (size_t)b * Cn * Nn;
#pragma unroll
    for (int et = 0; et < 4; ++et)
#pragma unroll
      for (int qt = 0; qt < 4; ++qt) {
        f32x4 o = *(const f32x4*)(lds + (size_t)(16 * qt + l15) * 1040 + (64 * wq + 16 * et + 4 * g) * 4);
        int q = m0 + 16 * qt + l15;
#pragma unroll
        for (int r = 0; r < 4; ++r) {
          int e = 64 * wq + 16 * et + 4 * g + r;
          size_t off = (size_t)e * Nn + q;
          ob[off] = zb[off] + (acc[et][qt][r] + o[r]) * inv[qt];
        }
      }
  }
}

// ---------------------------------------------------------------------------
extern "C" void kernel_launch(void* const* d_in, const int* in_sizes, int n_in,
                              void* d_out, int out_size, void* d_ws, size_t ws_size,
                              hipStream_t stream) {
  (void)in_sizes; (void)n_in; (void)out_size; (void)ws_size;
  const float* z  = (const float*)d_in[0];
  const float* x  = (const float*)d_in[1];
  const float* y  = (const float*)d_in[2];
  const float* Wq = (const float*)d_in[3];
  const float* bq = (const float*)d_in[4];
  const float* Wk = (const float*)d_in[5];
  const float* bk = (const float*)d_in[6];
  const float* Wv = (const float*)d_in[7];
  const float* bv = (const float*)d_in[8];
  float* out = (float*)d_out;

  unsigned short* qws = (unsigned short*)d_ws;            // [4][4096][32] bf16
  unsigned short* kws = qws + (size_t)Bn * Nn * Dn;       // [4][64][4096B] frag-ordered
  unsigned short* vws = kws + (size_t)Bn * Nn * Dn;       // [4][64][32768B] frag-ordered

  SA_proj2<<<256, 640, 0, stream>>>(x, y, z, Wq, bq, Wk, bk, Wv, bv, qws, kws, vws);
  SA_flash<<<256, 512, 0, stream>>>(qws, kws, vws, z, out);
}

// Round 7
// 170.662 us; speedup vs baseline: 1.3011x; 1.0100x over previous
//
#include <hip/hip_runtime.h>
#include <hip/hip_bf16.h>

#define Bn 4
#define Cn 256
#define Dn 32
#define Nn 4096

typedef __attribute__((ext_vector_type(8))) short short8;
typedef __attribute__((ext_vector_type(4))) float f32x4;

union U16 { uint4 u; short8 s; };

__device__ __forceinline__ unsigned short f2bf(float f) {
  union { __hip_bfloat16 h; unsigned short u; } c;
  c.h = __float2bfloat16(f);   // HW RNE cvt (pairs fuse to v_cvt_pk_bf16_f32)
  return c.u;
}

// ============================================================================
// Fused projection kernel — UNCHANGED from round 6 (measured-good; frag-
// ordered outputs so flash reads K/V fragments straight from L2).
//   qws: [B][N][32] bf16 rows. kws: [B][kt][t=4][chunk=64][16B].
//   vws: [B][kt][wq=4][frag=8][chunk=64][16B].
// k-map (everywhere): frag slot j (lane group g): k = 4g+j (j<4), 16+4g+(j-4).
// ============================================================================
__global__ __launch_bounds__(640, 1) void SA_proj2(
    const float* __restrict__ x, const float* __restrict__ y, const float* __restrict__ z,
    const float* __restrict__ Wq, const float* __restrict__ bq,
    const float* __restrict__ Wk, const float* __restrict__ bk,
    const float* __restrict__ Wv, const float* __restrict__ bv,
    unsigned short* __restrict__ qws, unsigned short* __restrict__ kws,
    unsigned short* __restrict__ vws)
{
  __shared__ char lds[3 * 33280];          // X,Y,Z tiles: [64 n][520 B] each
  const int bid = blockIdx.x, tid = threadIdx.x;
  const int lane = tid & 63, wv2 = tid >> 6;
  const int g = lane >> 4, l15 = lane & 15;
  const int b = bid >> 6, n0 = (bid & 63) << 6;
  const int kt = n0 >> 6;

  const float* src0 = x + (size_t)b * Cn * Nn;
  const float* src1 = y + (size_t)b * Cn * Nn;
  const float* src2 = z + (size_t)b * Cn * Nn;

  const int isv = (wv2 >= 2);
  const float* W    = isv ? Wv : (wv2 == 0 ? Wq : Wk);
  const float* bias = isv ? bv : (wv2 == 0 ? bq : bk);
  const int e0w = isv ? ((wv2 - 2) << 5) : 0;
  const char* myT = lds + (isv ? 2 : wv2) * 33280;

  const int cl = tid >> 2, fq = tid & 3;

  f32x4 sl0[4], sl1[4], sl2[4];
  auto stage_ld = [&](int ck) {
    const size_t row = (size_t)(ck * 128 + cl) * Nn + n0 + fq * 4;
#pragma unroll
    for (int i = 0; i < 4; ++i) sl0[i] = *(const f32x4*)(src0 + row + i * 16);
#pragma unroll
    for (int i = 0; i < 4; ++i) sl1[i] = *(const f32x4*)(src1 + row + i * 16);
#pragma unroll
    for (int i = 0; i < 4; ++i) sl2[i] = *(const f32x4*)(src2 + row + i * 16);
  };
  auto stage_wr = [&](int ck) {
    const int cb = (ck * 128 + cl) * 2;
#pragma unroll
    for (int i = 0; i < 4; ++i)
#pragma unroll
      for (int j = 0; j < 4; ++j) {
        char* rp = lds + (size_t)(fq * 4 + i * 16 + j) * 520 + cb;
        *(unsigned short*)(rp)         = f2bf(sl0[i][j]);
        *(unsigned short*)(rp + 33280) = f2bf(sl1[i][j]);
        *(unsigned short*)(rp + 66560) = f2bf(sl2[i][j]);
      }
  };

  f32x4 wf[2][4][2];
  auto w_ld = [&](int ck) {
#pragma unroll
    for (int et = 0; et < 2; ++et) {
      const float* wp = W + (size_t)(e0w + 16 * et + l15) * 256 + ck * 128 + 4 * g;
#pragma unroll
      for (int cc = 0; cc < 4; ++cc) {
        wf[et][cc][0] = *(const f32x4*)(wp + cc * 32);
        wf[et][cc][1] = *(const f32x4*)(wp + cc * 32 + 16);
      }
    }
  };
  short8 af[2][4];
  auto w_cvt = [&]() {
#pragma unroll
    for (int et = 0; et < 2; ++et)
#pragma unroll
      for (int cc = 0; cc < 4; ++cc) {
        short8 t8;
#pragma unroll
        for (int j = 0; j < 4; ++j) {
          t8[j]     = (short)f2bf(wf[et][cc][0][j]);
          t8[4 + j] = (short)f2bf(wf[et][cc][1][j]);
        }
        af[et][cc] = t8;
      }
  };

  f32x4 acc[2][4];
#pragma unroll
  for (int et = 0; et < 2; ++et)
#pragma unroll
    for (int ns = 0; ns < 4; ++ns) { acc[et][ns][0]=0.f; acc[et][ns][1]=0.f; acc[et][ns][2]=0.f; acc[et][ns][3]=0.f; }

  auto compute = [&](int ck) {
#pragma unroll
    for (int cc = 0; cc < 4; ++cc) {
      const int cbyte = (ck * 128 + cc * 32 + 4 * g) * 2;
#pragma unroll
      for (int ns = 0; ns < 4; ++ns) {
        const char* rp = myT + (size_t)(16 * ns + l15) * 520 + cbyte;
        U16 bb;
        bb.u.x = *(const unsigned*)rp;        bb.u.y = *(const unsigned*)(rp + 4);
        bb.u.z = *(const unsigned*)(rp + 32); bb.u.w = *(const unsigned*)(rp + 36);
#pragma unroll
        for (int et = 0; et < 2; ++et)
          acc[et][ns] = __builtin_amdgcn_mfma_f32_16x16x32_bf16(af[et][cc], bb.s, acc[et][ns], 0, 0, 0);
      }
    }
  };

  if (tid < 512) stage_ld(0);
  w_ld(0);
  if (tid < 512) stage_wr(0);
  __syncthreads();                         // A: chunk0 tiles ready
  w_cvt();
  if (tid < 512) stage_ld(1);
  compute(0);
  if (tid < 512) stage_wr(1);
  w_ld(1);
  __syncthreads();                         // B: chunk1 ready
  w_cvt();
  compute(1);
  __syncthreads();                         // C: LDS reusable

  float bvv[2][4];
#pragma unroll
  for (int et = 0; et < 2; ++et)
#pragma unroll
    for (int r = 0; r < 4; ++r) bvv[et][r] = bias[e0w + 16 * et + 4 * g + r];

  if (isv) {
    const int vw = wv2 - 2, Wt = vw >> 1, w1 = vw & 1;
#pragma unroll
    for (int et = 0; et < 2; ++et)
#pragma unroll
      for (int ns = 0; ns < 4; ++ns)
#pragma unroll
        for (int r = 0; r < 4; ++r) {
          int byte = Wt * 8192 + (((2 * w1 + et) << 1) + (ns >> 1)) * 1024
                   + ((l15 >> 2) * 16 + 4 * g + r) * 16 + (ns & 1) * 8 + (l15 & 3) * 2;
          *(unsigned short*)(lds + byte) = f2bf(acc[et][ns][r] + bvv[et][r]);
        }
  } else if (wv2 == 0) {
    char* base = lds + 66560;
#pragma unroll
    for (int et = 0; et < 2; ++et)
#pragma unroll
      for (int ns = 0; ns < 4; ++ns)
#pragma unroll
        for (int r = 0; r < 4; ++r) {
          int d = 16 * et + 4 * g + r;
          int n = 16 * ns + l15;
          *(unsigned short*)(base + (size_t)n * 80 + d * 2) = f2bf(acc[et][ns][r] + bvv[et][r]);
        }
  } else {
    char* base = lds + 71680;
#pragma unroll
    for (int et = 0; et < 2; ++et)
#pragma unroll
      for (int ns = 0; ns < 4; ++ns)
#pragma unroll
        for (int r = 0; r < 4; ++r) {
          int pos = ns * 1024 + g * 256 + l15 * 16 + et * 8 + r * 2;
          *(unsigned short*)(base + pos) = f2bf(acc[et][ns][r] + bvv[et][r]);
        }
  }
  __syncthreads();                         // D: repack visible

  if (tid < 512) {
    char* gb = (char*)vws + (size_t)b * Cn * Nn * 2 + (size_t)kt * 32768 + tid * 64;
    const char* lb = lds + tid * 64;
#pragma unroll
    for (int i = 0; i < 4; ++i)
      *(uint4*)(gb + i * 16) = *(const uint4*)(lb + i * 16);
  }
  if (wv2 == 0) {
    unsigned short* ob = qws + (size_t)b * Nn * Dn;
#pragma unroll
    for (int i = 0; i < 4; ++i) {
      int flat = 64 * i + lane;
      *(uint4*)((char*)ob + (size_t)n0 * 64 + flat * 16)
          = *(const uint4*)(lds + 66560 + (size_t)(flat >> 2) * 80 + (flat & 3) * 16);
    }
  } else if (wv2 == 1) {
    char* ob = (char*)kws + (size_t)b * Nn * Dn * 2 + (size_t)kt * 4096;
#pragma unroll
    for (int i = 0; i < 4; ++i) {
      int flat = 64 * i + lane;
      *(uint4*)(ob + flat * 16) = *(const uint4*)(lds + 71680 + flat * 16);
    }
  }
}

// ============================================================================
// Flash attention v4 + residual. Grid 256 x 512 thr (2 k-groups x 4 waves).
// K/V frags global->reg (L2-resident, prefetched; NEVER drained at barriers:
// raw s_barrier + lgkmcnt(0) only — T3/T4). ONE sync per iteration; P/alpha/
// flag double-buffered; PV delayed one tile so softmax(it) and PV(it-1) share
// a window and waves drift (cross-wave MFMA/VALU overlap). Exact math:
// same defer-max online softmax + exact cross-group combine as r6.
// ============================================================================
__global__ __launch_bounds__(512, 2) void SA_flash(
    const unsigned short* __restrict__ qws, const unsigned short* __restrict__ kws,
    const unsigned short* __restrict__ vws, const float* __restrict__ z,
    float* __restrict__ outp)
{
  __shared__ char lds[69760];
  // [0,32768): P frags, group gg at gg*16384, slot s at +s*8192.
  // [0,66560): combine scratch (epilogue only).
  // 66560 m_arr f32[2][64]; 67072 l_arr; 67584 a_arr f32[2slot][2gg][64];
  // 69632 f_arr u32[2slot][2gg][4].
  float*    m_arr = (float*)(lds + 66560);
  float*    l_arr = (float*)(lds + 67072);
  float*    a_arr = (float*)(lds + 67584);
  unsigned* f_arr = (unsigned*)(lds + 69632);

  const int bid = blockIdx.x;
  const int b    = (bid >> 1) & 3;     // XCD pairs share a batch -> K/V L2-resident
  const int mblk = ((bid >> 3) << 1) | (bid & 1);
  const int m0 = mblk * 64;
  const int tid = threadIdx.x, lane = tid & 63;
  const int wv = tid >> 6, gg = wv >> 2, wq = wv & 3;
  const int g = lane >> 4, l15 = lane & 15;

  char* Pg = lds + gg * 16384;

  const unsigned short* qb = qws + (size_t)b * Nn * Dn;
  const char* kb = (const char*)kws + (size_t)b * Nn * Dn * 2;
  const char* vb = (const char*)vws + (size_t)b * Cn * Nn * 2;

  // Q fragment (B operand): col q = 16wq + l15, k(d)-slots per k-map
  const int mw = m0 + 16 * wq;
  short8 qf;
  {
    const char* qp = (const char*)qb + (size_t)(mw + l15) * 64 + 8 * g;
    ushort4 q0 = *(const ushort4*)qp;
    ushort4 q1 = *(const ushort4*)(qp + 32);
    qf[0]=(short)q0.x; qf[1]=(short)q0.y; qf[2]=(short)q0.z; qf[3]=(short)q0.w;
    qf[4]=(short)q1.x; qf[5]=(short)q1.y; qf[6]=(short)q1.z; qf[7]=(short)q1.w;
  }

  f32x4 acc[4][4];                      // [et][qt]: e = 64wq+16et+4g+r, q = 16qt+l15
#pragma unroll
  for (int et = 0; et < 4; ++et)
#pragma unroll
    for (int qt = 0; qt < 4; ++qt) { acc[et][qt][0]=0.f; acc[et][qt][1]=0.f; acc[et][qt][2]=0.f; acc[et][qt][3]=0.f; }
  float m_run = -__builtin_inff(), l_run = 0.f;

  uint4 kfr[4], vfr[8];
  auto k_ld = [&](int t4) {
    const char* p = kb + (size_t)t4 * 4096 + lane * 16;
#pragma unroll
    for (int t = 0; t < 4; ++t) kfr[t] = *(const uint4*)(p + t * 1024);
  };
  auto v_ld = [&](int t4) {
    const char* p = vb + (size_t)t4 * 32768 + wq * 8192 + lane * 16;
#pragma unroll
    for (int f = 0; f < 8; ++f) vfr[f] = *(const uint4*)(p + f * 1024);
  };
  k_ld(gg);                             // K for window 0

  for (int it = 0; it < 33; ++it) {
    if (it > 0) {
      // ---- rescale (alpha from slot it-1) + PV(it-1)
      const int sl = (it - 1) & 1;
      uint4 fl = *(const uint4*)(f_arr + sl * 8 + gg * 4);
      if (fl.x | fl.y | fl.z | fl.w) {
        float al4[4];
#pragma unroll
        for (int qt = 0; qt < 4; ++qt) al4[qt] = a_arr[sl * 128 + gg * 64 + 16 * qt + l15];
#pragma unroll
        for (int et = 0; et < 4; ++et)
#pragma unroll
          for (int qt = 0; qt < 4; ++qt) {
            acc[et][qt][0]*=al4[qt]; acc[et][qt][1]*=al4[qt];
            acc[et][qt][2]*=al4[qt]; acc[et][qt][3]*=al4[qt];
          }
      }
      __builtin_amdgcn_s_setprio(1);
#pragma unroll
      for (int qt = 0; qt < 4; ++qt) {
#pragma unroll
        for (int ks = 0; ks < 2; ++ks) {
          short8 pfr = *(const short8*)(Pg + sl * 8192 + (qt * 2 + ks) * 1024 + lane * 16);
#pragma unroll
          for (int et = 0; et < 4; ++et) {
            U16 vu; vu.u = vfr[et * 2 + ks];
            acc[et][qt] = __builtin_amdgcn_mfma_f32_16x16x32_bf16(vu.s, pfr, acc[et][qt], 0, 0, 0);
          }
        }
      }
      __builtin_amdgcn_s_setprio(0);
    }
    if (it < 32) {
      v_ld(2 * it + gg);                // V(it): consumed in window it+1; stays
                                        // in flight across the raw barrier
      // ---- S^T from register K frags: rows n = 16t+4g+r, col q = l15
      f32x4 s[4];
      const f32x4 zero4 = {0.f, 0.f, 0.f, 0.f};
#pragma unroll
      for (int t = 0; t < 4; ++t) {
        U16 ku; ku.u = kfr[t];
        s[t] = __builtin_amdgcn_mfma_f32_16x16x32_bf16(ku.s, qf, zero4, 0, 0, 0);
      }
      if (it < 31) k_ld(2 * (it + 1) + gg);   // K(it+1) prefetch

      // ---- softmax for this wave's 16 q (exact, batched-max update)
      float pm = s[0][0];
#pragma unroll
      for (int t = 0; t < 4; ++t)
#pragma unroll
        for (int r = 0; r < 4; ++r) pm = fmaxf(pm, s[t][r]);
      pm = fmaxf(pm, __shfl_xor(pm, 16, 64));
      pm = fmaxf(pm, __shfl_xor(pm, 32, 64));
      int trig = __any(pm > m_run);
      float alpha = 1.0f;
      if (trig) {
        float mn = fmaxf(m_run, pm);
        alpha = __expf(m_run - mn);
        l_run *= alpha;
        m_run = mn;
      }
      float p[4][4]; float rs = 0.f;
#pragma unroll
      for (int t = 0; t < 4; ++t)
#pragma unroll
        for (int r = 0; r < 4; ++r) { float e = __expf(s[t][r] - m_run); p[t][r] = e; rs += e; }
      rs += __shfl_xor(rs, 16, 64);
      rs += __shfl_xor(rs, 32, 64);
      l_run += rs;

      // ---- P^T frags (lane-local) -> slot it&1
      short8 pf0, pf1;
      pf0[0]=(short)f2bf(p[0][0]); pf0[1]=(short)f2bf(p[0][1]);
      pf0[2]=(short)f2bf(p[0][2]); pf0[3]=(short)f2bf(p[0][3]);
      pf0[4]=(short)f2bf(p[1][0]); pf0[5]=(short)f2bf(p[1][1]);
      pf0[6]=(short)f2bf(p[1][2]); pf0[7]=(short)f2bf(p[1][3]);
      pf1[0]=(short)f2bf(p[2][0]); pf1[1]=(short)f2bf(p[2][1]);
      pf1[2]=(short)f2bf(p[2][2]); pf1[3]=(short)f2bf(p[2][3]);
      pf1[4]=(short)f2bf(p[3][0]); pf1[5]=(short)f2bf(p[3][1]);
      pf1[6]=(short)f2bf(p[3][2]); pf1[7]=(short)f2bf(p[3][3]);
      const int sw = it & 1;
      *(short8*)(Pg + sw * 8192 + (wq * 2 + 0) * 1024 + lane * 16) = pf0;
      *(short8*)(Pg + sw * 8192 + (wq * 2 + 1) * 1024 + lane * 16) = pf1;
      if (lane < 16) a_arr[sw * 128 + gg * 64 + 16 * wq + lane] = alpha;
      if (lane == 0) f_arr[sw * 8 + gg * 4 + wq] = (unsigned)trig;

      // ---- raw barrier: drain LDS only; V/K prefetches stay in flight (T4)
      asm volatile("s_waitcnt lgkmcnt(0)" ::: "memory");
      __builtin_amdgcn_s_barrier();
      __builtin_amdgcn_sched_barrier(0);
    }
  }

  // ---- exact cross-group combine, then epilogue by group 0
  if (lane < 16) {
    m_arr[gg * 64 + 16 * wq + lane] = m_run;
    l_arr[gg * 64 + 16 * wq + lane] = l_run;
  }
  __syncthreads();
  float fmy[4], inv[4];
#pragma unroll
  for (int qt = 0; qt < 4; ++qt) {
    int q = 16 * qt + l15;
    float mv0 = m_arr[q], mv1 = m_arr[64 + q];
    float lv0 = l_arr[q], lv1 = l_arr[64 + q];
    float M = fmaxf(mv0, mv1);
    float f0 = __expf(mv0 - M), f1 = __expf(mv1 - M);
    inv[qt] = 1.0f / (lv0 * f0 + lv1 * f1);
    fmy[qt] = gg ? f1 : f0;
  }
#pragma unroll
  for (int et = 0; et < 4; ++et)
#pragma unroll
    for (int qt = 0; qt < 4; ++qt) {
      acc[et][qt][0]*=fmy[qt]; acc[et][qt][1]*=fmy[qt];
      acc[et][qt][2]*=fmy[qt]; acc[et][qt][3]*=fmy[qt];
    }
  if (gg == 1) {
#pragma unroll
    for (int et = 0; et < 4; ++et)
#pragma unroll
      for (int qt = 0; qt < 4; ++qt)
        *(f32x4*)(lds + (size_t)(16 * qt + l15) * 1040 + (64 * wq + 16 * et + 4 * g) * 4) = acc[et][qt];
  }
  __syncthreads();
  if (gg == 0) {
    const float* zb = z    + (size_t)b * Cn * Nn;
    float*       ob = outp + (size_t)b * Cn * Nn;
#pragma unroll
    for (int et = 0; et < 4; ++et)
#pragma unroll
      for (int qt = 0; qt < 4; ++qt) {
        f32x4 o = *(const f32x4*)(lds + (size_t)(16 * qt + l15) * 1040 + (64 * wq + 16 * et + 4 * g) * 4);
        int q = m0 + 16 * qt + l15;
#pragma unroll
        for (int r = 0; r < 4; ++r) {
          int e = 64 * wq + 16 * et + 4 * g + r;
          size_t off = (size_t)e * Nn + q;
          ob[off] = zb[off] + (acc[et][qt][r] + o[r]) * inv[qt];
        }
      }
  }
}

// ---------------------------------------------------------------------------
extern "C" void kernel_launch(void* const* d_in, const int* in_sizes, int n_in,
                              void* d_out, int out_size, void* d_ws, size_t ws_size,
                              hipStream_t stream) {
  (void)in_sizes; (void)n_in; (void)out_size; (void)ws_size;
  const float* z  = (const float*)d_in[0];
  const float* x  = (const float*)d_in[1];
  const float* y  = (const float*)d_in[2];
  const float* Wq = (const float*)d_in[3];
  const float* bq = (const float*)d_in[4];
  const float* Wk = (const float*)d_in[5];
  const float* bk = (const float*)d_in[6];
  const float* Wv = (const float*)d_in[7];
  const float* bv = (const float*)d_in[8];
  float* out = (float*)d_out;

  unsigned short* qws = (unsigned short*)d_ws;            // [4][4096][32] bf16
  unsigned short* kws = qws + (size_t)Bn * Nn * Dn;       // [4][64][4096B] frag-ordered
  unsigned short* vws = kws + (size_t)Bn * Nn * Dn;       // [4][64][32768B] frag-ordered

  SA_proj2<<<256, 640, 0, stream>>>(x, y, z, Wq, bq, Wk, bk, Wv, bv, qws, kws, vws);
  SA_flash<<<256, 512, 0, stream>>>(qws, kws, vws, z, out);
}